// Round 18
// baseline (616.650 us; speedup 1.0000x reference)
//
#include <hip/hip_runtime.h>
#include <hip/hip_bf16.h>

// Problem constants (fixed by the reference)
#define NN 50000
#define TT 16
#define EE 800000

typedef __attribute__((ext_vector_type(8))) short short8;
typedef __attribute__((ext_vector_type(4))) float f32x4;

// ---------------- ws layout (bytes) ----------------
#define WS_DINV   0          // N f32 (deg counts, then dinv)
#define WS_SNORM  200704     // N f32
#define WS_WC     401408     // 192*16 f32
#define WS_WB     413696     // 192 f32
#define WS_W1EA   414464     // 128*4 f32 (e1W edge-attr cols)
#define WS_B1W2   416512     // 128 float2 (e1b, e2W)
#define WS_BA     417536     // 256 f32 GRU biasA
#define WS_BB     418560     // 256 f32 GRU biasB
#define WS_EMB    419840     // N*64 ushort (bf16 emb; 6.4MB)
#define WS_OFF    13219840   // (N+1) i32
#define WS_CUR    13420032   // N i32
#define WS_ROWV   13620224   // EE i32  (CSR src)
#define WS_COLV   16820224   // EE i32  (CSR dst)
#define WS_EIDV   20020224   // EE i32  (CSR -> original edge id)
#define WS_NRMV   23220224   // EE f32  (CSR edge norms)
#define WS_WFH    26420224   // GRU weight frags hi [36][64][8] ushort
#define WS_WFL    26457088   // GRU weight frags lo
#define WS_WEH    26493952   // edge W frags hi [8][4][64][8] ushort (32KB)
#define WS_AGGH   26560000   // N*T*16 ushort (25.6MB) [n][t][16]
#define WS_AGGL   52160000   // N*T*16 ushort (25.6MB)
// overlay inside AGGH region: ONLY written after k_gru9 fully completes (k_edge2).
#define WS_PREDV  26560000   // EE f32 (CSR-ordered edge preds)
#define WS_XB     77760000   // N*T*16 ushort (25.6MB) bf16 x — optional (ws_size gate)
#define WS_XB_END 103360000

static __device__ inline ushort f2bf(float v) {
    __hip_bfloat16 b = __float2bfloat16(v);
    return *(ushort*)&b;
}
static __device__ inline float bf2f(ushort u) {
    __hip_bfloat16 b; *(ushort*)&b = u;
    return __bfloat162float(b);
}
// fast RNE bf16 pack (identical result to __float2bfloat16 for finite v)
static __device__ inline ushort f2bf_fast(float v) {
    uint u = __float_as_uint(v);
    u += 0x7FFFu + ((u >> 16) & 1u);
    return (ushort)(u >> 16);
}
static __device__ inline f32x4 mfma1(short8 a, short8 b, f32x4 c) {
    return __builtin_amdgcn_mfma_f32_16x16x32_bf16(a, b, c, 0, 0, 0);
}
static __device__ inline f32x4 mfma3(short8 ah, short8 al, short8 bh, short8 bl, f32x4 c) {
    c = __builtin_amdgcn_mfma_f32_16x16x32_bf16(ah, bh, c, 0, 0, 0);
    c = __builtin_amdgcn_mfma_f32_16x16x32_bf16(ah, bl, c, 0, 0, 0);
    c = __builtin_amdgcn_mfma_f32_16x16x32_bf16(al, bh, c, 0, 0, 0);
    return c;
}
static __device__ inline f32x4 mfma2(short8 ah, short8 bh, short8 bl, f32x4 c) {
    c = __builtin_amdgcn_mfma_f32_16x16x32_bf16(ah, bh, c, 0, 0, 0);
    c = __builtin_amdgcn_mfma_f32_16x16x32_bf16(ah, bl, c, 0, 0, 0);
    return c;
}
static __device__ inline f32x4 mfma2a(short8 ah, short8 al, short8 bh, f32x4 c) {
    c = __builtin_amdgcn_mfma_f32_16x16x32_bf16(ah, bh, c, 0, 0, 0);
    c = __builtin_amdgcn_mfma_f32_16x16x32_bf16(al, bh, c, 0, 0, 0);
    return c;
}
static __device__ inline short8 ld8u(const ushort* p) {   // 8-B aligned LDS read
    short8 v;
    ((uint2*)&v)[0] = *(const uint2*)p;
    ((uint2*)&v)[1] = *(const uint2*)(p + 4);
    return v;
}

__global__ __launch_bounds__(256) void k_init(float* deg) {
    int n = blockIdx.x * 256 + threadIdx.x;
    if (n < NN) deg[n] = 1.0f;
}

__global__ __launch_bounds__(256) void k_deg(const int* __restrict__ ei, float* deg) {
    int e = blockIdx.x * 256 + threadIdx.x;
    if (e < EE) atomicAdd(&deg[ei[EE + e]], 1.0f);
}

// Exclusive scan of cnt[n] = deg[n]-1 (incoming degree). Single block, 1024 thr.
__global__ __launch_bounds__(1024) void k_scan(const float* __restrict__ deg,
                                               int* __restrict__ off,
                                               int* __restrict__ cursor) {
    __shared__ int wsum[16];
    __shared__ int carryS;
    int tid = threadIdx.x, lane = tid & 63, wv = tid >> 6;
    if (tid == 0) carryS = 0;
    __syncthreads();
    for (int base = 0; base < NN; base += 4096) {
        int i0 = base + tid * 4;
        int v[4];
        int tot = 0;
        for (int q = 0; q < 4; q++) {
            int i = i0 + q;
            v[q] = (i < NN) ? (int)deg[i] - 1 : 0;
            tot += v[q];
        }
        int inc = tot;
        for (int d = 1; d < 64; d <<= 1) {
            int tpl = __shfl_up(inc, d, 64);
            if (lane >= d) inc += tpl;
        }
        if (lane == 63) wsum[wv] = inc;
        __syncthreads();
        int wexcl = 0;
        for (int k = 0; k < 16; k++) wexcl += (k < wv) ? wsum[k] : 0;
        int run = carryS + wexcl + inc - tot;
        __syncthreads();
        for (int q = 0; q < 4; q++) {
            int i = i0 + q;
            if (i < NN) { off[i] = run; cursor[i] = run; }
            run += v[q];
        }
        if (tid == 1023) carryS = run;
        __syncthreads();
    }
    if (threadIdx.x == 0) off[NN] = carryS;
}

__global__ __launch_bounds__(256) void k_dinv(float* deg_dinv) {
    int n = blockIdx.x * 256 + threadIdx.x;
    if (n < NN) deg_dinv[n] = rsqrtf(deg_dinv[n]);
}

// Fill CSR buckets: rowv/colv/eidv/nrmv per destination.
__global__ __launch_bounds__(256) void k_fill(const int* __restrict__ ei,
                                              const float* __restrict__ dinv,
                                              int* __restrict__ cursor,
                                              int* __restrict__ rowv,
                                              int* __restrict__ colv,
                                              int* __restrict__ eidv,
                                              float* __restrict__ nrmv) {
    int e = blockIdx.x * 256 + threadIdx.x;
    if (e >= EE) return;
    int r = ei[e], c = ei[EE + e];
    int p = atomicAdd(&cursor[c], 1);
    rowv[p] = r;
    colv[p] = c;
    eidv[p] = e;
    nrmv[p] = dinv[r] * dinv[c];
}

// Wc = W_ih @ gcn_W (192x16 row-major), wb = W_ih @ gcn_b
__global__ __launch_bounds__(256) void k_prep(const float* __restrict__ Wih,
                                              const float* __restrict__ gcnW,
                                              const float* __restrict__ gcnb,
                                              float* wc, float* wb) {
    int tid = blockIdx.x * 256 + threadIdx.x;
    if (tid < 3072) {
        int f = tid & 15, row = tid >> 4;
        float s = 0.f;
        for (int k = 0; k < 64; k++) s += Wih[row * 64 + k] * gcnW[k * 16 + f];
        wc[row * 16 + f] = s;
    } else if (tid < 3264) {
        int row = tid - 3072;
        float s = 0.f;
        for (int k = 0; k < 64; k++) s += Wih[row * 64 + k] * gcnb[k];
        wb[row] = s;
    }
}

// Packed-row value of the 256x96 GRU weight matrix:
// rows 0..127: [Whh | Wc | 0] (r,z); 128..191: [Whh_n | 0]; 192..255: [0 | Wc_n | 0]
static __device__ inline float pk_val(const float* whh, const float* wc, int row, int k) {
    if (row < 128)  return (k < 64) ? whh[row * 64 + k] : ((k < 80) ? wc[row * 16 + k - 64] : 0.f);
    if (row < 192)  return (k < 64) ? whh[row * 64 + k] : 0.f;
    return (k >= 64 && k < 80) ? wc[(row - 64) * 16 + k - 64] : 0.f;
}

// Build GRU weight MFMA fragments (hi/lo), frag layout [cc=c*4+w][64][8] + biases.
__global__ __launch_bounds__(256) void k_prep3(const float* __restrict__ whh,
                                               const float* __restrict__ wc,
                                               const float* __restrict__ wb,
                                               const float* __restrict__ bih,
                                               const float* __restrict__ bhh,
                                               ushort* __restrict__ wfh,
                                               ushort* __restrict__ wfl,
                                               float* __restrict__ biasA,
                                               float* __restrict__ biasB) {
    const int ci[9] = {0, 0, 0, 1, 1, 1, 2, 2, 3};
    const int ck[9] = {0, 1, 2, 0, 1, 2, 0, 1, 2};
    int idx = blockIdx.x * 256 + threadIdx.x;
    if (idx < 2304) {
        int cc = idx >> 6, l = idx & 63;
        int c = cc >> 2, w = cc & 3;
        int lg = l >> 4, lr = l & 15;
        int row = ci[c] * 64 + w * 16 + lr;
        for (int e = 0; e < 8; e++) {
            int k = ck[c] * 32 + lg * 8 + e;
            float v = pk_val(whh, wc, row, k);
            uint b = __float_as_uint(v);
            uint hi = b & 0xFFFF0000u;
            float lo = v - __uint_as_float(hi);
            wfh[idx * 8 + e] = (ushort)(hi >> 16);
            wfl[idx * 8 + e] = (ushort)(__float_as_uint(lo) >> 16);
        }
    } else if (idx < 2560) {
        int row = idx - 2304;
        int g = (row < 192) ? row : row - 64;
        float ba, bb;
        if (row < 128)      { ba = bih[row] + bhh[row]; bb = wb[row]; }
        else if (row < 192) { ba = bhh[row];            bb = 0.f; }
        else                { ba = bih[g];              bb = wb[g]; }
        biasA[row] = ba;
        biasB[row] = bb;
    }
}

// Edge-MLP weight frags (bf16 single plane) [nt][ks][l][8], K=128 only;
// + w1ea (edge-attr cols of e1W) + (e1b,e2W) table.
__global__ __launch_bounds__(256) void k_prepw(const float* __restrict__ e1W,
                                               const float* __restrict__ e1b,
                                               const float* __restrict__ e2W,
                                               ushort* __restrict__ weh,
                                               float* __restrict__ w1ea,
                                               float2* __restrict__ b1w2) {
    int idx = blockIdx.x * 256 + threadIdx.x;
    if (idx < 16384) {
        int cc = idx >> 9;            // (nt*4+ks)
        int li = (idx >> 3) & 63;
        int e  = idx & 7;
        int nt = cc >> 2, ks = cc & 3;
        int row = nt * 16 + (li & 15);
        int k   = ks * 32 + (li >> 4) * 8 + e;
        weh[idx] = f2bf(e1W[row * 132 + k]);
    } else if (idx < 16896) {
        int t = idx - 16384;
        int h = t >> 2, j = t & 3;
        w1ea[t] = e1W[h * 132 + 128 + j];
    } else if (idx < 17024) {
        int h = idx - 16896;
        b1w2[h] = make_float2(e1b[h], e2W[h]);
    }
}

// Convert x (N*T*16 = 12.8M f32) to bf16.
__global__ __launch_bounds__(256) void k_cvtx(const float* __restrict__ x,
                                              ushort* __restrict__ xb) {
    int i = blockIdx.x * 256 + threadIdx.x;   // over 3.2M float4s
    if (i >= NN * TT * 4) return;
    float4 v = ((const float4*)x)[i];
    ushort4 o;
    o.x = f2bf_fast(v.x); o.y = f2bf_fast(v.y);
    o.z = f2bf_fast(v.z); o.w = f2bf_fast(v.w);
    ((ushort4*)xb)[i] = o;
}

// Gather v4b: t-pair per wave (round-17 structure) with bf16 x — t-pair working
// set 2x1.6MB fits the 4MB per-XCD L2, collapsing L2-miss traffic.
__global__ __launch_bounds__(256) void k_gather4b(const ushort* __restrict__ xb,
                                                  const float* __restrict__ dinv,
                                                  const int* __restrict__ off,
                                                  const int* __restrict__ rowv,
                                                  const float* __restrict__ nrmv,
                                                  ushort* __restrict__ aggh,
                                                  ushort* __restrict__ aggl,
                                                  float* __restrict__ snorm) {
    int blk = blockIdx.x;
    int t0 = blk & 7;
    int g = blk >> 3;
    int wv = threadIdx.x >> 6, lane = threadIdx.x & 63;
    int n = g * 4 + wv;
    int es = lane >> 2, f4 = lane & 3;
    int s = off[n], e = off[n + 1];
    const ushort* x0 = xb + (size_t)t0 * (NN * 16) + f4 * 4;
    const ushort* x1 = x0 + (size_t)8 * NN * 16;
    float4 a0 = make_float4(0.f, 0.f, 0.f, 0.f);
    float4 a1 = make_float4(0.f, 0.f, 0.f, 0.f);
    float sacc = 0.f;
    if (t0 == 0) {
        for (int p = s + es; p < e; p += 16) {
            int r = rowv[p];
            float nr = nrmv[p];
            uint2 u0 = *(const uint2*)(x0 + (size_t)r * 16);
            uint2 u1 = *(const uint2*)(x1 + (size_t)r * 16);
            a0.x += nr * __uint_as_float(u0.x << 16);
            a0.y += nr * __uint_as_float(u0.x & 0xFFFF0000u);
            a0.z += nr * __uint_as_float(u0.y << 16);
            a0.w += nr * __uint_as_float(u0.y & 0xFFFF0000u);
            a1.x += nr * __uint_as_float(u1.x << 16);
            a1.y += nr * __uint_as_float(u1.x & 0xFFFF0000u);
            a1.z += nr * __uint_as_float(u1.y << 16);
            a1.w += nr * __uint_as_float(u1.y & 0xFFFF0000u);
            sacc += nr;        // same across f4 lanes; es-axis reduce makes it exact
        }
    } else {
        for (int p = s + es; p < e; p += 16) {
            int r = rowv[p];
            float nr = nrmv[p];
            uint2 u0 = *(const uint2*)(x0 + (size_t)r * 16);
            uint2 u1 = *(const uint2*)(x1 + (size_t)r * 16);
            a0.x += nr * __uint_as_float(u0.x << 16);
            a0.y += nr * __uint_as_float(u0.x & 0xFFFF0000u);
            a0.z += nr * __uint_as_float(u0.y << 16);
            a0.w += nr * __uint_as_float(u0.y & 0xFFFF0000u);
            a1.x += nr * __uint_as_float(u1.x << 16);
            a1.y += nr * __uint_as_float(u1.x & 0xFFFF0000u);
            a1.z += nr * __uint_as_float(u1.y << 16);
            a1.w += nr * __uint_as_float(u1.y & 0xFFFF0000u);
        }
    }
    #pragma unroll
    for (int m = 4; m < 64; m <<= 1) {
        a0.x += __shfl_xor(a0.x, m, 64);
        a0.y += __shfl_xor(a0.y, m, 64);
        a0.z += __shfl_xor(a0.z, m, 64);
        a0.w += __shfl_xor(a0.w, m, 64);
        a1.x += __shfl_xor(a1.x, m, 64);
        a1.y += __shfl_xor(a1.y, m, 64);
        a1.z += __shfl_xor(a1.z, m, 64);
        a1.w += __shfl_xor(a1.w, m, 64);
    }
    if (es == 0) {
        float dn = dinv[n], d2 = dn * dn;
        uint2 u0 = *(const uint2*)(x0 + (size_t)n * 16);
        uint2 u1 = *(const uint2*)(x1 + (size_t)n * 16);
        a0.x += d2 * __uint_as_float(u0.x << 16);
        a0.y += d2 * __uint_as_float(u0.x & 0xFFFF0000u);
        a0.z += d2 * __uint_as_float(u0.y << 16);
        a0.w += d2 * __uint_as_float(u0.y & 0xFFFF0000u);
        a1.x += d2 * __uint_as_float(u1.x << 16);
        a1.y += d2 * __uint_as_float(u1.x & 0xFFFF0000u);
        a1.z += d2 * __uint_as_float(u1.y << 16);
        a1.w += d2 * __uint_as_float(u1.y & 0xFFFF0000u);
        ushort4 hv, lv;
        hv.x = f2bf_fast(a0.x); lv.x = f2bf_fast(a0.x - bf2f(hv.x));
        hv.y = f2bf_fast(a0.y); lv.y = f2bf_fast(a0.y - bf2f(hv.y));
        hv.z = f2bf_fast(a0.z); lv.z = f2bf_fast(a0.z - bf2f(hv.z));
        hv.w = f2bf_fast(a0.w); lv.w = f2bf_fast(a0.w - bf2f(hv.w));
        size_t ao0 = (size_t)n * 256 + t0 * 16 + f4 * 4;
        *(ushort4*)(aggh + ao0) = hv;
        *(ushort4*)(aggl + ao0) = lv;
        hv.x = f2bf_fast(a1.x); lv.x = f2bf_fast(a1.x - bf2f(hv.x));
        hv.y = f2bf_fast(a1.y); lv.y = f2bf_fast(a1.y - bf2f(hv.y));
        hv.z = f2bf_fast(a1.z); lv.z = f2bf_fast(a1.z - bf2f(hv.z));
        hv.w = f2bf_fast(a1.w); lv.w = f2bf_fast(a1.w - bf2f(hv.w));
        *(ushort4*)(aggh + ao0 + 128) = hv;   // t1 = t0+8 -> +8*16 elems
        *(ushort4*)(aggl + ao0 + 128) = lv;
    }
    if (t0 == 0) {
        sacc += __shfl_xor(sacc, 4, 64);
        sacc += __shfl_xor(sacc, 8, 64);
        sacc += __shfl_xor(sacc, 16, 64);
        sacc += __shfl_xor(sacc, 32, 64);
        if (lane == 0) {
            float dn = dinv[n];
            snorm[n] = sacc + dn * dn;
        }
    }
}

// Gather v4 (round-17 validated, f32 x) — fallback when ws is too small for xb.
__global__ __launch_bounds__(256) void k_gather4(const float* __restrict__ x,
                                                 const float* __restrict__ dinv,
                                                 const int* __restrict__ off,
                                                 const int* __restrict__ rowv,
                                                 const float* __restrict__ nrmv,
                                                 ushort* __restrict__ aggh,
                                                 ushort* __restrict__ aggl,
                                                 float* __restrict__ snorm) {
    int blk = blockIdx.x;
    int t0 = blk & 7;
    int g = blk >> 3;
    int wv = threadIdx.x >> 6, lane = threadIdx.x & 63;
    int n = g * 4 + wv;
    int es = lane >> 2, f4 = lane & 3;
    int s = off[n], e = off[n + 1];
    const float* xt0 = x + (size_t)t0 * (NN * 16) + f4 * 4;
    const float* xt1 = xt0 + (size_t)8 * NN * 16;
    float4 a0 = make_float4(0.f, 0.f, 0.f, 0.f);
    float4 a1 = make_float4(0.f, 0.f, 0.f, 0.f);
    float sacc = 0.f;
    if (t0 == 0) {
        for (int p = s + es; p < e; p += 16) {
            int r = rowv[p];
            float nr = nrmv[p];
            float4 v0 = *(const float4*)(xt0 + (size_t)r * 16);
            float4 v1 = *(const float4*)(xt1 + (size_t)r * 16);
            a0.x += nr * v0.x; a0.y += nr * v0.y; a0.z += nr * v0.z; a0.w += nr * v0.w;
            a1.x += nr * v1.x; a1.y += nr * v1.y; a1.z += nr * v1.z; a1.w += nr * v1.w;
            sacc += nr;
        }
    } else {
        for (int p = s + es; p < e; p += 16) {
            int r = rowv[p];
            float nr = nrmv[p];
            float4 v0 = *(const float4*)(xt0 + (size_t)r * 16);
            float4 v1 = *(const float4*)(xt1 + (size_t)r * 16);
            a0.x += nr * v0.x; a0.y += nr * v0.y; a0.z += nr * v0.z; a0.w += nr * v0.w;
            a1.x += nr * v1.x; a1.y += nr * v1.y; a1.z += nr * v1.z; a1.w += nr * v1.w;
        }
    }
    #pragma unroll
    for (int m = 4; m < 64; m <<= 1) {
        a0.x += __shfl_xor(a0.x, m, 64);
        a0.y += __shfl_xor(a0.y, m, 64);
        a0.z += __shfl_xor(a0.z, m, 64);
        a0.w += __shfl_xor(a0.w, m, 64);
        a1.x += __shfl_xor(a1.x, m, 64);
        a1.y += __shfl_xor(a1.y, m, 64);
        a1.z += __shfl_xor(a1.z, m, 64);
        a1.w += __shfl_xor(a1.w, m, 64);
    }
    if (es == 0) {
        float dn = dinv[n], d2 = dn * dn;
        float4 v0 = *(const float4*)(xt0 + (size_t)n * 16);
        float4 v1 = *(const float4*)(xt1 + (size_t)n * 16);
        a0.x += d2 * v0.x; a0.y += d2 * v0.y; a0.z += d2 * v0.z; a0.w += d2 * v0.w;
        a1.x += d2 * v1.x; a1.y += d2 * v1.y; a1.z += d2 * v1.z; a1.w += d2 * v1.w;
        ushort4 hv, lv;
        hv.x = f2bf_fast(a0.x); lv.x = f2bf_fast(a0.x - bf2f(hv.x));
        hv.y = f2bf_fast(a0.y); lv.y = f2bf_fast(a0.y - bf2f(hv.y));
        hv.z = f2bf_fast(a0.z); lv.z = f2bf_fast(a0.z - bf2f(hv.z));
        hv.w = f2bf_fast(a0.w); lv.w = f2bf_fast(a0.w - bf2f(hv.w));
        size_t ao0 = (size_t)n * 256 + t0 * 16 + f4 * 4;
        *(ushort4*)(aggh + ao0) = hv;
        *(ushort4*)(aggl + ao0) = lv;
        hv.x = f2bf_fast(a1.x); lv.x = f2bf_fast(a1.x - bf2f(hv.x));
        hv.y = f2bf_fast(a1.y); lv.y = f2bf_fast(a1.y - bf2f(hv.y));
        hv.z = f2bf_fast(a1.z); lv.z = f2bf_fast(a1.z - bf2f(hv.z));
        hv.w = f2bf_fast(a1.w); lv.w = f2bf_fast(a1.w - bf2f(hv.w));
        *(ushort4*)(aggh + ao0 + 128) = hv;
        *(ushort4*)(aggl + ao0 + 128) = lv;
    }
    if (t0 == 0) {
        sacc += __shfl_xor(sacc, 4, 64);
        sacc += __shfl_xor(sacc, 8, 64);
        sacc += __shfl_xor(sacc, 16, 64);
        sacc += __shfl_xor(sacc, 32, 64);
        if (lane == 0) {
            float dn = dinv[n];
            snorm[n] = sacc + dn * dn;
        }
    }
}

// MFMA GRU v9 (validated round 14/15): (256,2) bound -> 128-VGPR budget, no
// spill, 4 blocks/CU. Emits bf16 emb ONLY (into WS_EMB region — NOT the agg
// overlay, so no inter-block race).
__global__ __launch_bounds__(256, 2) void k_gru9(const ushort* __restrict__ aggh,
                                                 const ushort* __restrict__ aggl,
                                                 const float* __restrict__ snorm,
                                                 const ushort* __restrict__ wfh,
                                                 const ushort* __restrict__ wfl,
                                                 const float* __restrict__ biasA,
                                                 const float* __restrict__ biasB,
                                                 ushort* __restrict__ embh) {
    __shared__ ushort sWl[12 * 64 * 8];   // 12288 B: lo chunks 6..8 ([cc-24][64][8])
    __shared__ ushort sH[2][64][68];      // 17408 B, stride-68 = measured conflict-free
    int tid = threadIdx.x;
    int w = tid >> 6, l = tid & 63;
    int lg = l >> 4, lr = l & 15;
    int base = blockIdx.x * 64;
    int j = w * 16 + lr;

    for (int i = tid; i < 768; i += 256)
        ((uint4*)sWl)[i] = ((const uint4*)wfl)[1536 + i];   // chunks 6..8 (cc 24..35)
    for (int i = tid; i < 64 * 68; i += 256)
        ((ushort*)sH[0])[i] = 0;     // only buffer 0 needs zeroing

    // Weight-hi fragments resident in registers for the whole kernel (36 VGPR).
    short8 bh[9];
    #pragma unroll
    for (int c = 0; c < 9; c++)
        bh[c] = *(const short8*)(wfh + ((c * 4 + w) * 64 + l) * 8);

    float bA[4], bB[4];
    #pragma unroll
    for (int i = 0; i < 4; i++) {
        bA[i] = biasA[i * 64 + j];
        bB[i] = biasB[i * 64 + j];
    }
    float snr[4][4], hold[4][4];
    #pragma unroll
    for (int tl = 0; tl < 4; tl++)
        #pragma unroll
        for (int q = 0; q < 4; q++) {
            int n = base + tl * 16 + lg * 4 + q;
            snr[tl][q] = snorm[min(n, NN - 1)];
            hold[tl][q] = 0.f;
        }
    int nA[4];
    #pragma unroll
    for (int tl = 0; tl < 4; tl++) nA[tl] = min(base + tl * 16 + lr, NN - 1);

    __syncthreads();

    int cur = 0;
    #pragma unroll 1
    for (int t = 0; t < TT; t++) {
        #pragma unroll
        for (int tl = 0; tl < 4; tl++) {
            int nd = tl * 16 + lr;
            const ushort* ph = &sH[cur][nd][lg * 8];
            short8 Ah0 = ld8u(ph);
            short8 Ah1 = ld8u(ph + 32);
            short8 Ah2 = {0,0,0,0,0,0,0,0};
            short8 Al2 = {0,0,0,0,0,0,0,0};
            if (lg < 2) {
                size_t ao = (size_t)nA[tl] * 256 + t * 16 + lg * 8;
                Ah2 = *(const short8*)(aggh + ao);
                Al2 = *(const short8*)(aggl + ao);
            }
            short8 bl6 = ld8u(sWl + ((0 * 4 + w) * 64 + l) * 8);
            short8 bl7 = ld8u(sWl + ((1 * 4 + w) * 64 + l) * 8);
            short8 bl8 = ld8u(sWl + ((2 * 4 + w) * 64 + l) * 8);

            f32x4 a0, a1, a2, a3;
            #pragma unroll
            for (int q = 0; q < 4; q++) {
                a0[q] = bA[0] + snr[tl][q] * bB[0];
                a1[q] = bA[1] + snr[tl][q] * bB[1];
                a2[q] = bA[2] + snr[tl][q] * bB[2];
                a3[q] = bA[3] + snr[tl][q] * bB[3];
            }
            // r-gate (sigmoid-damped): bf16 weights, agg keeps lo
            a0 = mfma1(Ah0, bh[0], a0);
            a0 = mfma1(Ah1, bh[1], a0);
            a0 = mfma2a(Ah2, Al2, bh[2], a0);
            // z-gate
            a1 = mfma1(Ah0, bh[3], a1);
            a1 = mfma1(Ah1, bh[4], a1);
            a1 = mfma2a(Ah2, Al2, bh[5], a1);
            // n-gate paths: full precision
            a2 = mfma2(Ah0, bh[6], bl6, a2);
            a2 = mfma2(Ah1, bh[7], bl7, a2);
            a3 = mfma3(Ah2, Al2, bh[8], bl8, a3);

            #pragma unroll
            for (int q = 0; q < 4; q++) {
                float r = __builtin_amdgcn_rcpf(1.f + __expf(-a0[q]));
                float z = __builtin_amdgcn_rcpf(1.f + __expf(-a1[q]));
                float a = a3[q] + r * a2[q];
                float e2 = __expf(2.f * a);
                float nnv = 1.f - 2.f * __builtin_amdgcn_rcpf(e2 + 1.f); // tanh, inf-safe
                float hv = nnv + z * (hold[tl][q] - nnv);
                hold[tl][q] = hv;
                int ndw = tl * 16 + lg * 4 + q;
                sH[cur ^ 1][ndw][j] = f2bf_fast(hv);   // bf16-RNE h for next t
            }
        }
        __syncthreads();   // h_{t+1} fully written before next t reads it
        cur ^= 1;
    }

    #pragma unroll
    for (int tl = 0; tl < 4; tl++)
        #pragma unroll
        for (int q = 0; q < 4; q++) {
            int n = base + tl * 16 + lg * 4 + q;
            if (n < NN) embh[(size_t)n * 64 + j] = f2bf_fast(hold[tl][q]);
        }
}

// Edge MLP via single-pass bf16 MFMA, CSR-ordered (dst-locality), weights in LDS,
// edge_attr as exact-f32 VALU epilogue. predv segment-summed in k_node (no atomics).
__global__ __launch_bounds__(256) void k_edge2(const ushort* __restrict__ embh,
                                               const float* __restrict__ ea,
                                               const ushort* __restrict__ weh,
                                               const float* __restrict__ w1ea,
                                               const float2* __restrict__ b1w2,
                                               const int* __restrict__ rowv,
                                               const int* __restrict__ colv,
                                               const int* __restrict__ eidv,
                                               const float* __restrict__ e2b,
                                               float* __restrict__ pred_edge,
                                               float* __restrict__ predv) {
    __shared__ ushort sW[16384];   // 32 KB: e1W bf16 frags [nt][ks][64][8]
    int tid = threadIdx.x;
    for (int i = tid; i < 2048; i += 256)
        ((uint4*)sW)[i] = ((const uint4*)weh)[i];

    int w = tid >> 6, l = tid & 63;
    int lg = l >> 4, lr = l & 15;
    int pbase = (blockIdx.x * 4 + w) * 32;

    short8 Ah[2][4];
    #pragma unroll
    for (int s = 0; s < 2; s++) {
        int p = pbase + s * 16 + lr;
        int r = rowv[p], c = colv[p];
        #pragma unroll
        for (int ks = 0; ks < 4; ks++) {
            int src = (ks < 2) ? r : c;
            int kk = (ks & 1) * 32 + lg * 8;
            Ah[s][ks] = *(const short8*)(embh + (size_t)src * 64 + kk);
        }
    }
    float4 eav[2][4];
    #pragma unroll
    for (int s = 0; s < 2; s++)
        #pragma unroll
        for (int q = 0; q < 4; q++) {
            int p = pbase + s * 16 + lg * 4 + q;
            eav[s][q] = *(const float4*)(ea + (size_t)eidv[p] * 4);
        }
    __syncthreads();

    float esum[2][4];
    #pragma unroll
    for (int s = 0; s < 2; s++)
        #pragma unroll
        for (int q = 0; q < 4; q++) esum[s][q] = 0.f;

    #pragma unroll 1
    for (int nt = 0; nt < 8; nt++) {
        f32x4 acc[2] = {{0.f, 0.f, 0.f, 0.f}, {0.f, 0.f, 0.f, 0.f}};
        #pragma unroll
        for (int ks = 0; ks < 4; ks++) {
            int offs = ((nt * 4 + ks) * 64 + l) * 8;
            short8 bh = ld8u(sW + offs);
            acc[0] = mfma1(Ah[0][ks], bh, acc[0]);
            acc[1] = mfma1(Ah[1][ks], bh, acc[1]);
        }
        int h = nt * 16 + lr;
        float2 bw = b1w2[h];
        float4 wv = *(const float4*)(w1ea + h * 4);
        #pragma unroll
        for (int s = 0; s < 2; s++)
            #pragma unroll
            for (int q = 0; q < 4; q++) {
                float pre = acc[s][q] + bw.x
                          + wv.x * eav[s][q].x + wv.y * eav[s][q].y
                          + wv.z * eav[s][q].z + wv.w * eav[s][q].w;
                esum[s][q] += fmaxf(pre, 0.f) * bw.y;
            }
    }
    for (int m = 1; m < 16; m <<= 1)
        #pragma unroll
        for (int s = 0; s < 2; s++)
            #pragma unroll
            for (int q = 0; q < 4; q++)
                esum[s][q] += __shfl_xor(esum[s][q], m, 64);
    if (lr == 0) {
        float eb = e2b[0];
        #pragma unroll
        for (int s = 0; s < 2; s++)
            #pragma unroll
            for (int q = 0; q < 4; q++) {
                int p = pbase + s * 16 + lg * 4 + q;
                float pv = esum[s][q] + eb;
                predv[p] = pv;
                pred_edge[eidv[p]] = pv;
            }
    }
}

// Node MLP + flow segment-sum (no atomics): one wave per node; bf16 emb input.
__global__ __launch_bounds__(256) void k_node(const ushort* __restrict__ embh,
                                              const float* __restrict__ predv,
                                              const int* __restrict__ off,
                                              const float* __restrict__ p1W,
                                              const float* __restrict__ p1b,
                                              const float* __restrict__ p2W,
                                              const float* __restrict__ p2b,
                                              float* __restrict__ out) {
    int w = threadIdx.x >> 6, j = threadIdx.x & 63;
    int n = blockIdx.x * 4 + w;
    if (n >= NN) return;
    int s = off[n], e = off[n + 1];
    float fsum = 0.f;
    for (int i = s + j; i < e; i += 64) fsum += predv[i];
    for (int m = 1; m < 64; m <<= 1) fsum += __shfl_xor(fsum, m, 64);
    const float* wrow = p1W + j * 65;
    const ushort* ev = embh + (size_t)n * 64;
    float acc = p1b[j];
    #pragma unroll
    for (int f4 = 0; f4 < 16; f4++) {
        uint2 u = *(const uint2*)(ev + f4 * 4);
        acc += wrow[f4 * 4 + 0] * __uint_as_float(u.x << 16);
        acc += wrow[f4 * 4 + 1] * __uint_as_float(u.x & 0xFFFF0000u);
        acc += wrow[f4 * 4 + 2] * __uint_as_float(u.y << 16);
        acc += wrow[f4 * 4 + 3] * __uint_as_float(u.y & 0xFFFF0000u);
    }
    acc += wrow[64] * fsum;
    float val = p2W[j] * fmaxf(acc, 0.f);
    for (int m = 1; m < 64; m <<= 1) val += __shfl_xor(val, m, 64);
    if (j == 0) out[n] = val + p2b[0];
}

extern "C" void kernel_launch(void* const* d_in, const int* in_sizes, int n_in,
                              void* d_out, int out_size, void* d_ws, size_t ws_size,
                              hipStream_t stream) {
    (void)in_sizes; (void)n_in; (void)out_size;
    const float* x    = (const float*)d_in[0];
    const float* ea   = (const float*)d_in[1];
    const float* gcnW = (const float*)d_in[2];
    const float* gcnb = (const float*)d_in[3];
    const float* Wih  = (const float*)d_in[4];
    const float* Whh  = (const float*)d_in[5];
    const float* bih  = (const float*)d_in[6];
    const float* bhh  = (const float*)d_in[7];
    const float* e1W  = (const float*)d_in[8];
    const float* e1b  = (const float*)d_in[9];
    const float* e2W  = (const float*)d_in[10];
    const float* e2b  = (const float*)d_in[11];
    const float* p1W  = (const float*)d_in[12];
    const float* p1b  = (const float*)d_in[13];
    const float* p2W  = (const float*)d_in[14];
    const float* p2b  = (const float*)d_in[15];
    const int*   ei   = (const int*)d_in[16];

    char* ws = (char*)d_ws;
    float*  dinv  = (float*)(ws + WS_DINV);
    float*  snorm = (float*)(ws + WS_SNORM);
    float*  wc    = (float*)(ws + WS_WC);
    float*  wb    = (float*)(ws + WS_WB);
    float*  w1ea  = (float*)(ws + WS_W1EA);
    float2* b1w2  = (float2*)(ws + WS_B1W2);
    float*  biasA = (float*)(ws + WS_BA);
    float*  biasB = (float*)(ws + WS_BB);
    ushort* embh  = (ushort*)(ws + WS_EMB);
    int*    off   = (int*)(ws + WS_OFF);
    int*    cur   = (int*)(ws + WS_CUR);
    int*    rowv  = (int*)(ws + WS_ROWV);
    int*    colv  = (int*)(ws + WS_COLV);
    int*    eidv  = (int*)(ws + WS_EIDV);
    float*  nrmv  = (float*)(ws + WS_NRMV);
    ushort* wfh   = (ushort*)(ws + WS_WFH);
    ushort* wfl   = (ushort*)(ws + WS_WFL);
    ushort* weh   = (ushort*)(ws + WS_WEH);
    ushort* aggh  = (ushort*)(ws + WS_AGGH);
    ushort* aggl  = (ushort*)(ws + WS_AGGL);
    float*  predv = (float*)(ws + WS_PREDV);
    ushort* xb    = (ushort*)(ws + WS_XB);

    float* pred_node = (float*)d_out;
    float* pred_edge = (float*)d_out + NN;

    k_init<<<(NN + 255) / 256, 256, 0, stream>>>(dinv);
    k_deg<<<(EE + 255) / 256, 256, 0, stream>>>(ei, dinv);
    k_scan<<<1, 1024, 0, stream>>>(dinv, off, cur);
    k_dinv<<<(NN + 255) / 256, 256, 0, stream>>>(dinv);
    k_prep<<<13, 256, 0, stream>>>(Wih, gcnW, gcnb, wc, wb);
    k_prep3<<<10, 256, 0, stream>>>(Whh, wc, wb, bih, bhh, wfh, wfl, biasA, biasB);
    k_prepw<<<67, 256, 0, stream>>>(e1W, e1b, e2W, weh, w1ea, b1w2);
    k_fill<<<(EE + 255) / 256, 256, 0, stream>>>(ei, dinv, cur, rowv, colv, eidv, nrmv);
    if (ws_size >= (size_t)WS_XB_END) {
        k_cvtx<<<(NN * TT * 4 + 255) / 256, 256, 0, stream>>>(x, xb);
        k_gather4b<<<(NN / 4) * 8, 256, 0, stream>>>(xb, dinv, off, rowv, nrmv, aggh, aggl, snorm);
    } else {
        k_gather4<<<(NN / 4) * 8, 256, 0, stream>>>(x, dinv, off, rowv, nrmv, aggh, aggl, snorm);
    }
    k_gru9<<<(NN + 63) / 64, 256, 0, stream>>>(aggh, aggl, snorm, wfh, wfl, biasA, biasB, embh);
    k_edge2<<<EE / 128, 256, 0, stream>>>(embh, ea, weh, w1ea, b1w2,
                                          rowv, colv, eidv, e2b, pred_edge, predv);
    k_node<<<(NN + 3) / 4, 256, 0, stream>>>(embh, predv, off, p1W, p1b, p2W, p2b, pred_node);
}

// Round 19
// 514.516 us; speedup vs baseline: 1.1985x; 1.1985x over previous
//
#include <hip/hip_runtime.h>
#include <hip/hip_bf16.h>

// Problem constants (fixed by the reference)
#define NN 50000
#define TT 16
#define EE 800000

typedef __attribute__((ext_vector_type(8))) short short8;
typedef __attribute__((ext_vector_type(4))) float f32x4;

// ---------------- ws layout (bytes) ----------------
#define WS_DINV   0          // N f32 (deg counts, then dinv)
#define WS_SNORM  200704     // N f32
#define WS_WC     401408     // 192*16 f32
#define WS_WB     413696     // 192 f32
#define WS_W1EA   414464     // 128*4 f32 (e1W edge-attr cols)
#define WS_B1W2   416512     // 128 float2 (e1b, e2W)
#define WS_BA     417536     // 256 f32 GRU biasA
#define WS_BB     418560     // 256 f32 GRU biasB
#define WS_EMB    419840     // N*64 ushort (bf16 emb; 6.4MB)
#define WS_OFF    13219840   // (N+1) i32
#define WS_CUR    13420032   // N i32
#define WS_ROWV   13620224   // EE i32  (CSR src)
#define WS_COLV   16820224   // EE i32  (CSR dst)
#define WS_EIDV   20020224   // EE i32  (CSR -> original edge id)
#define WS_NRMV   23220224   // EE f32  (CSR edge norms)
#define WS_WFH    26420224   // GRU weight frags hi [36][64][8] ushort
#define WS_WFL    26457088   // GRU weight frags lo
#define WS_WEH    26493952   // edge W frags hi [8][4][64][8] ushort (32KB)
#define WS_AGGH   26560000   // N*T*16 ushort (25.6MB) [n][t][16]
#define WS_AGGL   52160000   // N*T*16 ushort (25.6MB)
// overlay inside AGGH region: ONLY written after k_gru9 fully completes (k_edge2).
#define WS_PREDV  26560000   // EE f32 (CSR-ordered edge preds)
#define WS_XB     77760000   // N*T*16 ushort (25.6MB) bf16 x, NODE-MAJOR [n][t][16]
#define WS_XB_END 103360000

static __device__ inline ushort f2bf(float v) {
    __hip_bfloat16 b = __float2bfloat16(v);
    return *(ushort*)&b;
}
static __device__ inline float bf2f(ushort u) {
    __hip_bfloat16 b; *(ushort*)&b = u;
    return __bfloat162float(b);
}
// fast RNE bf16 pack (identical result to __float2bfloat16 for finite v)
static __device__ inline ushort f2bf_fast(float v) {
    uint u = __float_as_uint(v);
    u += 0x7FFFu + ((u >> 16) & 1u);
    return (ushort)(u >> 16);
}
static __device__ inline float bflo(uint u) { return __uint_as_float(u << 16); }
static __device__ inline float bfhi(uint u) { return __uint_as_float(u & 0xFFFF0000u); }
static __device__ inline f32x4 mfma1(short8 a, short8 b, f32x4 c) {
    return __builtin_amdgcn_mfma_f32_16x16x32_bf16(a, b, c, 0, 0, 0);
}
static __device__ inline f32x4 mfma3(short8 ah, short8 al, short8 bh, short8 bl, f32x4 c) {
    c = __builtin_amdgcn_mfma_f32_16x16x32_bf16(ah, bh, c, 0, 0, 0);
    c = __builtin_amdgcn_mfma_f32_16x16x32_bf16(ah, bl, c, 0, 0, 0);
    c = __builtin_amdgcn_mfma_f32_16x16x32_bf16(al, bh, c, 0, 0, 0);
    return c;
}
static __device__ inline f32x4 mfma2(short8 ah, short8 bh, short8 bl, f32x4 c) {
    c = __builtin_amdgcn_mfma_f32_16x16x32_bf16(ah, bh, c, 0, 0, 0);
    c = __builtin_amdgcn_mfma_f32_16x16x32_bf16(ah, bl, c, 0, 0, 0);
    return c;
}
static __device__ inline f32x4 mfma2a(short8 ah, short8 al, short8 bh, f32x4 c) {
    c = __builtin_amdgcn_mfma_f32_16x16x32_bf16(ah, bh, c, 0, 0, 0);
    c = __builtin_amdgcn_mfma_f32_16x16x32_bf16(al, bh, c, 0, 0, 0);
    return c;
}
static __device__ inline short8 ld8u(const ushort* p) {   // 8-B aligned LDS read
    short8 v;
    ((uint2*)&v)[0] = *(const uint2*)p;
    ((uint2*)&v)[1] = *(const uint2*)(p + 4);
    return v;
}

__global__ __launch_bounds__(256) void k_init(float* deg) {
    int n = blockIdx.x * 256 + threadIdx.x;
    if (n < NN) deg[n] = 1.0f;
}

__global__ __launch_bounds__(256) void k_deg(const int* __restrict__ ei, float* deg) {
    int e = blockIdx.x * 256 + threadIdx.x;
    if (e < EE) atomicAdd(&deg[ei[EE + e]], 1.0f);
}

// Exclusive scan of cnt[n] = deg[n]-1 (incoming degree). Single block, 1024 thr.
__global__ __launch_bounds__(1024) void k_scan(const float* __restrict__ deg,
                                               int* __restrict__ off,
                                               int* __restrict__ cursor) {
    __shared__ int wsum[16];
    __shared__ int carryS;
    int tid = threadIdx.x, lane = tid & 63, wv = tid >> 6;
    if (tid == 0) carryS = 0;
    __syncthreads();
    for (int base = 0; base < NN; base += 4096) {
        int i0 = base + tid * 4;
        int v[4];
        int tot = 0;
        for (int q = 0; q < 4; q++) {
            int i = i0 + q;
            v[q] = (i < NN) ? (int)deg[i] - 1 : 0;
            tot += v[q];
        }
        int inc = tot;
        for (int d = 1; d < 64; d <<= 1) {
            int tpl = __shfl_up(inc, d, 64);
            if (lane >= d) inc += tpl;
        }
        if (lane == 63) wsum[wv] = inc;
        __syncthreads();
        int wexcl = 0;
        for (int k = 0; k < 16; k++) wexcl += (k < wv) ? wsum[k] : 0;
        int run = carryS + wexcl + inc - tot;
        __syncthreads();
        for (int q = 0; q < 4; q++) {
            int i = i0 + q;
            if (i < NN) { off[i] = run; cursor[i] = run; }
            run += v[q];
        }
        if (tid == 1023) carryS = run;
        __syncthreads();
    }
    if (threadIdx.x == 0) off[NN] = carryS;
}

__global__ __launch_bounds__(256) void k_dinv(float* deg_dinv) {
    int n = blockIdx.x * 256 + threadIdx.x;
    if (n < NN) deg_dinv[n] = rsqrtf(deg_dinv[n]);
}

// Fill CSR buckets: rowv/colv/eidv/nrmv per destination.
__global__ __launch_bounds__(256) void k_fill(const int* __restrict__ ei,
                                              const float* __restrict__ dinv,
                                              int* __restrict__ cursor,
                                              int* __restrict__ rowv,
                                              int* __restrict__ colv,
                                              int* __restrict__ eidv,
                                              float* __restrict__ nrmv) {
    int e = blockIdx.x * 256 + threadIdx.x;
    if (e >= EE) return;
    int r = ei[e], c = ei[EE + e];
    int p = atomicAdd(&cursor[c], 1);
    rowv[p] = r;
    colv[p] = c;
    eidv[p] = e;
    nrmv[p] = dinv[r] * dinv[c];
}

// Wc = W_ih @ gcn_W (192x16 row-major), wb = W_ih @ gcn_b
__global__ __launch_bounds__(256) void k_prep(const float* __restrict__ Wih,
                                              const float* __restrict__ gcnW,
                                              const float* __restrict__ gcnb,
                                              float* wc, float* wb) {
    int tid = blockIdx.x * 256 + threadIdx.x;
    if (tid < 3072) {
        int f = tid & 15, row = tid >> 4;
        float s = 0.f;
        for (int k = 0; k < 64; k++) s += Wih[row * 64 + k] * gcnW[k * 16 + f];
        wc[row * 16 + f] = s;
    } else if (tid < 3264) {
        int row = tid - 3072;
        float s = 0.f;
        for (int k = 0; k < 64; k++) s += Wih[row * 64 + k] * gcnb[k];
        wb[row] = s;
    }
}

// Packed-row value of the 256x96 GRU weight matrix:
// rows 0..127: [Whh | Wc | 0] (r,z); 128..191: [Whh_n | 0]; 192..255: [0 | Wc_n | 0]
static __device__ inline float pk_val(const float* whh, const float* wc, int row, int k) {
    if (row < 128)  return (k < 64) ? whh[row * 64 + k] : ((k < 80) ? wc[row * 16 + k - 64] : 0.f);
    if (row < 192)  return (k < 64) ? whh[row * 64 + k] : 0.f;
    return (k >= 64 && k < 80) ? wc[(row - 64) * 16 + k - 64] : 0.f;
}

// Build GRU weight MFMA fragments (hi/lo), frag layout [cc=c*4+w][64][8] + biases.
__global__ __launch_bounds__(256) void k_prep3(const float* __restrict__ whh,
                                               const float* __restrict__ wc,
                                               const float* __restrict__ wb,
                                               const float* __restrict__ bih,
                                               const float* __restrict__ bhh,
                                               ushort* __restrict__ wfh,
                                               ushort* __restrict__ wfl,
                                               float* __restrict__ biasA,
                                               float* __restrict__ biasB) {
    const int ci[9] = {0, 0, 0, 1, 1, 1, 2, 2, 3};
    const int ck[9] = {0, 1, 2, 0, 1, 2, 0, 1, 2};
    int idx = blockIdx.x * 256 + threadIdx.x;
    if (idx < 2304) {
        int cc = idx >> 6, l = idx & 63;
        int c = cc >> 2, w = cc & 3;
        int lg = l >> 4, lr = l & 15;
        int row = ci[c] * 64 + w * 16 + lr;
        for (int e = 0; e < 8; e++) {
            int k = ck[c] * 32 + lg * 8 + e;
            float v = pk_val(whh, wc, row, k);
            uint b = __float_as_uint(v);
            uint hi = b & 0xFFFF0000u;
            float lo = v - __uint_as_float(hi);
            wfh[idx * 8 + e] = (ushort)(hi >> 16);
            wfl[idx * 8 + e] = (ushort)(__float_as_uint(lo) >> 16);
        }
    } else if (idx < 2560) {
        int row = idx - 2304;
        int g = (row < 192) ? row : row - 64;
        float ba, bb;
        if (row < 128)      { ba = bih[row] + bhh[row]; bb = wb[row]; }
        else if (row < 192) { ba = bhh[row];            bb = 0.f; }
        else                { ba = bih[g];              bb = wb[g]; }
        biasA[row] = ba;
        biasB[row] = bb;
    }
}

// Edge-MLP weight frags (bf16 single plane) [nt][ks][l][8], K=128 only;
// + w1ea (edge-attr cols of e1W) + (e1b,e2W) table.
__global__ __launch_bounds__(256) void k_prepw(const float* __restrict__ e1W,
                                               const float* __restrict__ e1b,
                                               const float* __restrict__ e2W,
                                               ushort* __restrict__ weh,
                                               float* __restrict__ w1ea,
                                               float2* __restrict__ b1w2) {
    int idx = blockIdx.x * 256 + threadIdx.x;
    if (idx < 16384) {
        int cc = idx >> 9;            // (nt*4+ks)
        int li = (idx >> 3) & 63;
        int e  = idx & 7;
        int nt = cc >> 2, ks = cc & 3;
        int row = nt * 16 + (li & 15);
        int k   = ks * 32 + (li >> 4) * 8 + e;
        weh[idx] = f2bf(e1W[row * 132 + k]);
    } else if (idx < 16896) {
        int t = idx - 16384;
        int h = t >> 2, j = t & 3;
        w1ea[t] = e1W[h * 132 + 128 + j];
    } else if (idx < 17024) {
        int h = idx - 16896;
        b1w2[h] = make_float2(e1b[h], e2W[h]);
    }
}

// Transpose-convert x [t][n][16] f32 -> xb [n][t][16] bf16.
// Wave per node; lane = (t = lane>>2, f4 = lane&3): read float4, write coalesced.
__global__ __launch_bounds__(256) void k_cvtx2(const float* __restrict__ x,
                                               ushort* __restrict__ xb) {
    int wv = threadIdx.x >> 6, lane = threadIdx.x & 63;
    int n = blockIdx.x * 4 + wv;          // NN%4==0
    int t = lane >> 2, f4 = lane & 3;
    float4 v = *(const float4*)(x + (size_t)t * (NN * 16) + (size_t)n * 16 + f4 * 4);
    ushort4 o;
    o.x = f2bf_fast(v.x); o.y = f2bf_fast(v.y);
    o.z = f2bf_fast(v.z); o.w = f2bf_fast(v.w);
    *(ushort4*)(xb + (size_t)n * 256 + lane * 4) = o;
}

// Gather v5: node-major xb ([n][t][16] bf16). ONE wave per node; lane owns
// (t = lane>>2, f4 = lane&3) exclusively -> lane addr = r*256 + lane*4, so each
// edge is ONE coalesced 512-B wave load covering all 16 t's. ZERO shuffles:
// accumulators are lane-private; store is one coalesced 512-B row (agg layout
// [n][t][16] = n*256 + lane*4 matches gru9). snorm is lane-redundant Σnrmv.
__global__ __launch_bounds__(256) void k_gather5(const ushort* __restrict__ xb,
                                                 const float* __restrict__ dinv,
                                                 const int* __restrict__ off,
                                                 const int* __restrict__ rowv,
                                                 const float* __restrict__ nrmv,
                                                 ushort* __restrict__ aggh,
                                                 ushort* __restrict__ aggl,
                                                 float* __restrict__ snorm) {
    int wv = threadIdx.x >> 6, lane = threadIdx.x & 63;
    int n = blockIdx.x * 4 + wv;          // NN%4==0
    int s = off[n], e = off[n + 1];
    uint loff = (uint)lane * 4;           // ushort offset within a 256-elem row
    float ax = 0.f, ay = 0.f, az = 0.f, aw = 0.f, sacc = 0.f;
    int p = s;
    for (; p + 1 < e; p += 2) {           // unroll-2: 2 independent 512-B loads in flight
        int r0 = rowv[p], r1 = rowv[p + 1];
        float n0 = nrmv[p], n1 = nrmv[p + 1];
        uint2 u0 = *(const uint2*)(xb + (size_t)r0 * 256 + loff);
        uint2 u1 = *(const uint2*)(xb + (size_t)r1 * 256 + loff);
        ax += n0 * bflo(u0.x); ay += n0 * bfhi(u0.x);
        az += n0 * bflo(u0.y); aw += n0 * bfhi(u0.y);
        ax += n1 * bflo(u1.x); ay += n1 * bfhi(u1.x);
        az += n1 * bflo(u1.y); aw += n1 * bfhi(u1.y);
        sacc += n0 + n1;
    }
    if (p < e) {
        int r0 = rowv[p];
        float n0 = nrmv[p];
        uint2 u0 = *(const uint2*)(xb + (size_t)r0 * 256 + loff);
        ax += n0 * bflo(u0.x); ay += n0 * bfhi(u0.x);
        az += n0 * bflo(u0.y); aw += n0 * bfhi(u0.y);
        sacc += n0;
    }
    float dn = dinv[n], d2 = dn * dn;
    uint2 us = *(const uint2*)(xb + (size_t)n * 256 + loff);
    ax += d2 * bflo(us.x); ay += d2 * bfhi(us.x);
    az += d2 * bflo(us.y); aw += d2 * bfhi(us.y);
    ushort4 hv, lv;
    hv.x = f2bf_fast(ax); lv.x = f2bf_fast(ax - bf2f(hv.x));
    hv.y = f2bf_fast(ay); lv.y = f2bf_fast(ay - bf2f(hv.y));
    hv.z = f2bf_fast(az); lv.z = f2bf_fast(az - bf2f(hv.z));
    hv.w = f2bf_fast(aw); lv.w = f2bf_fast(aw - bf2f(hv.w));
    size_t ao = (size_t)n * 256 + loff;
    *(ushort4*)(aggh + ao) = hv;
    *(ushort4*)(aggl + ao) = lv;
    if (lane == 0) snorm[n] = sacc + d2;
}

// Gather v4 (round-17 validated, f32 x, [t][n][16]) — fallback when ws too small.
__global__ __launch_bounds__(256) void k_gather4(const float* __restrict__ x,
                                                 const float* __restrict__ dinv,
                                                 const int* __restrict__ off,
                                                 const int* __restrict__ rowv,
                                                 const float* __restrict__ nrmv,
                                                 ushort* __restrict__ aggh,
                                                 ushort* __restrict__ aggl,
                                                 float* __restrict__ snorm) {
    int blk = blockIdx.x;
    int t0 = blk & 7;
    int g = blk >> 3;
    int wv = threadIdx.x >> 6, lane = threadIdx.x & 63;
    int n = g * 4 + wv;
    int es = lane >> 2, f4 = lane & 3;
    int s = off[n], e = off[n + 1];
    const float* xt0 = x + (size_t)t0 * (NN * 16) + f4 * 4;
    const float* xt1 = xt0 + (size_t)8 * NN * 16;
    float4 a0 = make_float4(0.f, 0.f, 0.f, 0.f);
    float4 a1 = make_float4(0.f, 0.f, 0.f, 0.f);
    float sacc = 0.f;
    for (int p = s + es; p < e; p += 16) {
        int r = rowv[p];
        float nr = nrmv[p];
        float4 v0 = *(const float4*)(xt0 + (size_t)r * 16);
        float4 v1 = *(const float4*)(xt1 + (size_t)r * 16);
        a0.x += nr * v0.x; a0.y += nr * v0.y; a0.z += nr * v0.z; a0.w += nr * v0.w;
        a1.x += nr * v1.x; a1.y += nr * v1.y; a1.z += nr * v1.z; a1.w += nr * v1.w;
        if (t0 == 0) sacc += nr;
    }
    #pragma unroll
    for (int m = 4; m < 64; m <<= 1) {
        a0.x += __shfl_xor(a0.x, m, 64);
        a0.y += __shfl_xor(a0.y, m, 64);
        a0.z += __shfl_xor(a0.z, m, 64);
        a0.w += __shfl_xor(a0.w, m, 64);
        a1.x += __shfl_xor(a1.x, m, 64);
        a1.y += __shfl_xor(a1.y, m, 64);
        a1.z += __shfl_xor(a1.z, m, 64);
        a1.w += __shfl_xor(a1.w, m, 64);
    }
    if (es == 0) {
        float dn = dinv[n], d2 = dn * dn;
        float4 v0 = *(const float4*)(xt0 + (size_t)n * 16);
        float4 v1 = *(const float4*)(xt1 + (size_t)n * 16);
        a0.x += d2 * v0.x; a0.y += d2 * v0.y; a0.z += d2 * v0.z; a0.w += d2 * v0.w;
        a1.x += d2 * v1.x; a1.y += d2 * v1.y; a1.z += d2 * v1.z; a1.w += d2 * v1.w;
        ushort4 hv, lv;
        hv.x = f2bf_fast(a0.x); lv.x = f2bf_fast(a0.x - bf2f(hv.x));
        hv.y = f2bf_fast(a0.y); lv.y = f2bf_fast(a0.y - bf2f(hv.y));
        hv.z = f2bf_fast(a0.z); lv.z = f2bf_fast(a0.z - bf2f(hv.z));
        hv.w = f2bf_fast(a0.w); lv.w = f2bf_fast(a0.w - bf2f(hv.w));
        size_t ao0 = (size_t)n * 256 + t0 * 16 + f4 * 4;
        *(ushort4*)(aggh + ao0) = hv;
        *(ushort4*)(aggl + ao0) = lv;
        hv.x = f2bf_fast(a1.x); lv.x = f2bf_fast(a1.x - bf2f(hv.x));
        hv.y = f2bf_fast(a1.y); lv.y = f2bf_fast(a1.y - bf2f(hv.y));
        hv.z = f2bf_fast(a1.z); lv.z = f2bf_fast(a1.z - bf2f(hv.z));
        hv.w = f2bf_fast(a1.w); lv.w = f2bf_fast(a1.w - bf2f(hv.w));
        *(ushort4*)(aggh + ao0 + 128) = hv;
        *(ushort4*)(aggl + ao0 + 128) = lv;
    }
    if (t0 == 0) {
        sacc += __shfl_xor(sacc, 4, 64);
        sacc += __shfl_xor(sacc, 8, 64);
        sacc += __shfl_xor(sacc, 16, 64);
        sacc += __shfl_xor(sacc, 32, 64);
        if (lane == 0) {
            float dn = dinv[n];
            snorm[n] = sacc + dn * dn;
        }
    }
}

// MFMA GRU v9 (validated round 14/15): (256,2) bound -> 128-VGPR budget, no
// spill, 4 blocks/CU. Emits bf16 emb ONLY (into WS_EMB region — NOT the agg
// overlay, so no inter-block race).
__global__ __launch_bounds__(256, 2) void k_gru9(const ushort* __restrict__ aggh,
                                                 const ushort* __restrict__ aggl,
                                                 const float* __restrict__ snorm,
                                                 const ushort* __restrict__ wfh,
                                                 const ushort* __restrict__ wfl,
                                                 const float* __restrict__ biasA,
                                                 const float* __restrict__ biasB,
                                                 ushort* __restrict__ embh) {
    __shared__ ushort sWl[12 * 64 * 8];   // 12288 B: lo chunks 6..8 ([cc-24][64][8])
    __shared__ ushort sH[2][64][68];      // 17408 B, stride-68 = measured conflict-free
    int tid = threadIdx.x;
    int w = tid >> 6, l = tid & 63;
    int lg = l >> 4, lr = l & 15;
    int base = blockIdx.x * 64;
    int j = w * 16 + lr;

    for (int i = tid; i < 768; i += 256)
        ((uint4*)sWl)[i] = ((const uint4*)wfl)[1536 + i];   // chunks 6..8 (cc 24..35)
    for (int i = tid; i < 64 * 68; i += 256)
        ((ushort*)sH[0])[i] = 0;     // only buffer 0 needs zeroing

    // Weight-hi fragments resident in registers for the whole kernel (36 VGPR).
    short8 bh[9];
    #pragma unroll
    for (int c = 0; c < 9; c++)
        bh[c] = *(const short8*)(wfh + ((c * 4 + w) * 64 + l) * 8);

    float bA[4], bB[4];
    #pragma unroll
    for (int i = 0; i < 4; i++) {
        bA[i] = biasA[i * 64 + j];
        bB[i] = biasB[i * 64 + j];
    }
    float snr[4][4], hold[4][4];
    #pragma unroll
    for (int tl = 0; tl < 4; tl++)
        #pragma unroll
        for (int q = 0; q < 4; q++) {
            int n = base + tl * 16 + lg * 4 + q;
            snr[tl][q] = snorm[min(n, NN - 1)];
            hold[tl][q] = 0.f;
        }
    int nA[4];
    #pragma unroll
    for (int tl = 0; tl < 4; tl++) nA[tl] = min(base + tl * 16 + lr, NN - 1);

    __syncthreads();

    int cur = 0;
    #pragma unroll 1
    for (int t = 0; t < TT; t++) {
        #pragma unroll
        for (int tl = 0; tl < 4; tl++) {
            int nd = tl * 16 + lr;
            const ushort* ph = &sH[cur][nd][lg * 8];
            short8 Ah0 = ld8u(ph);
            short8 Ah1 = ld8u(ph + 32);
            short8 Ah2 = {0,0,0,0,0,0,0,0};
            short8 Al2 = {0,0,0,0,0,0,0,0};
            if (lg < 2) {
                size_t ao = (size_t)nA[tl] * 256 + t * 16 + lg * 8;
                Ah2 = *(const short8*)(aggh + ao);
                Al2 = *(const short8*)(aggl + ao);
            }
            short8 bl6 = ld8u(sWl + ((0 * 4 + w) * 64 + l) * 8);
            short8 bl7 = ld8u(sWl + ((1 * 4 + w) * 64 + l) * 8);
            short8 bl8 = ld8u(sWl + ((2 * 4 + w) * 64 + l) * 8);

            f32x4 a0, a1, a2, a3;
            #pragma unroll
            for (int q = 0; q < 4; q++) {
                a0[q] = bA[0] + snr[tl][q] * bB[0];
                a1[q] = bA[1] + snr[tl][q] * bB[1];
                a2[q] = bA[2] + snr[tl][q] * bB[2];
                a3[q] = bA[3] + snr[tl][q] * bB[3];
            }
            // r-gate (sigmoid-damped): bf16 weights, agg keeps lo
            a0 = mfma1(Ah0, bh[0], a0);
            a0 = mfma1(Ah1, bh[1], a0);
            a0 = mfma2a(Ah2, Al2, bh[2], a0);
            // z-gate
            a1 = mfma1(Ah0, bh[3], a1);
            a1 = mfma1(Ah1, bh[4], a1);
            a1 = mfma2a(Ah2, Al2, bh[5], a1);
            // n-gate paths: full precision
            a2 = mfma2(Ah0, bh[6], bl6, a2);
            a2 = mfma2(Ah1, bh[7], bl7, a2);
            a3 = mfma3(Ah2, Al2, bh[8], bl8, a3);

            #pragma unroll
            for (int q = 0; q < 4; q++) {
                float r = __builtin_amdgcn_rcpf(1.f + __expf(-a0[q]));
                float z = __builtin_amdgcn_rcpf(1.f + __expf(-a1[q]));
                float a = a3[q] + r * a2[q];
                float e2 = __expf(2.f * a);
                float nnv = 1.f - 2.f * __builtin_amdgcn_rcpf(e2 + 1.f); // tanh, inf-safe
                float hv = nnv + z * (hold[tl][q] - nnv);
                hold[tl][q] = hv;
                int ndw = tl * 16 + lg * 4 + q;
                sH[cur ^ 1][ndw][j] = f2bf_fast(hv);   // bf16-RNE h for next t
            }
        }
        __syncthreads();   // h_{t+1} fully written before next t reads it
        cur ^= 1;
    }

    #pragma unroll
    for (int tl = 0; tl < 4; tl++)
        #pragma unroll
        for (int q = 0; q < 4; q++) {
            int n = base + tl * 16 + lg * 4 + q;
            if (n < NN) embh[(size_t)n * 64 + j] = f2bf_fast(hold[tl][q]);
        }
}

// Edge MLP via single-pass bf16 MFMA, CSR-ordered (dst-locality), weights in LDS,
// edge_attr as exact-f32 VALU epilogue. predv segment-summed in k_node (no atomics).
__global__ __launch_bounds__(256) void k_edge2(const ushort* __restrict__ embh,
                                               const float* __restrict__ ea,
                                               const ushort* __restrict__ weh,
                                               const float* __restrict__ w1ea,
                                               const float2* __restrict__ b1w2,
                                               const int* __restrict__ rowv,
                                               const int* __restrict__ colv,
                                               const int* __restrict__ eidv,
                                               const float* __restrict__ e2b,
                                               float* __restrict__ pred_edge,
                                               float* __restrict__ predv) {
    __shared__ ushort sW[16384];   // 32 KB: e1W bf16 frags [nt][ks][64][8]
    int tid = threadIdx.x;
    for (int i = tid; i < 2048; i += 256)
        ((uint4*)sW)[i] = ((const uint4*)weh)[i];

    int w = tid >> 6, l = tid & 63;
    int lg = l >> 4, lr = l & 15;
    int pbase = (blockIdx.x * 4 + w) * 32;

    short8 Ah[2][4];
    #pragma unroll
    for (int s = 0; s < 2; s++) {
        int p = pbase + s * 16 + lr;
        int r = rowv[p], c = colv[p];
        #pragma unroll
        for (int ks = 0; ks < 4; ks++) {
            int src = (ks < 2) ? r : c;
            int kk = (ks & 1) * 32 + lg * 8;
            Ah[s][ks] = *(const short8*)(embh + (size_t)src * 64 + kk);
        }
    }
    float4 eav[2][4];
    #pragma unroll
    for (int s = 0; s < 2; s++)
        #pragma unroll
        for (int q = 0; q < 4; q++) {
            int p = pbase + s * 16 + lg * 4 + q;
            eav[s][q] = *(const float4*)(ea + (size_t)eidv[p] * 4);
        }
    __syncthreads();

    float esum[2][4];
    #pragma unroll
    for (int s = 0; s < 2; s++)
        #pragma unroll
        for (int q = 0; q < 4; q++) esum[s][q] = 0.f;

    #pragma unroll 1
    for (int nt = 0; nt < 8; nt++) {
        f32x4 acc[2] = {{0.f, 0.f, 0.f, 0.f}, {0.f, 0.f, 0.f, 0.f}};
        #pragma unroll
        for (int ks = 0; ks < 4; ks++) {
            int offs = ((nt * 4 + ks) * 64 + l) * 8;
            short8 bh = ld8u(sW + offs);
            acc[0] = mfma1(Ah[0][ks], bh, acc[0]);
            acc[1] = mfma1(Ah[1][ks], bh, acc[1]);
        }
        int h = nt * 16 + lr;
        float2 bw = b1w2[h];
        float4 wv = *(const float4*)(w1ea + h * 4);
        #pragma unroll
        for (int s = 0; s < 2; s++)
            #pragma unroll
            for (int q = 0; q < 4; q++) {
                float pre = acc[s][q] + bw.x
                          + wv.x * eav[s][q].x + wv.y * eav[s][q].y
                          + wv.z * eav[s][q].z + wv.w * eav[s][q].w;
                esum[s][q] += fmaxf(pre, 0.f) * bw.y;
            }
    }
    for (int m = 1; m < 16; m <<= 1)
        #pragma unroll
        for (int s = 0; s < 2; s++)
            #pragma unroll
            for (int q = 0; q < 4; q++)
                esum[s][q] += __shfl_xor(esum[s][q], m, 64);
    if (lr == 0) {
        float eb = e2b[0];
        #pragma unroll
        for (int s = 0; s < 2; s++)
            #pragma unroll
            for (int q = 0; q < 4; q++) {
                int p = pbase + s * 16 + lg * 4 + q;
                float pv = esum[s][q] + eb;
                predv[p] = pv;
                pred_edge[eidv[p]] = pv;
            }
    }
}

// Node MLP + flow segment-sum (no atomics): one wave per node; bf16 emb input.
__global__ __launch_bounds__(256) void k_node(const ushort* __restrict__ embh,
                                              const float* __restrict__ predv,
                                              const int* __restrict__ off,
                                              const float* __restrict__ p1W,
                                              const float* __restrict__ p1b,
                                              const float* __restrict__ p2W,
                                              const float* __restrict__ p2b,
                                              float* __restrict__ out) {
    int w = threadIdx.x >> 6, j = threadIdx.x & 63;
    int n = blockIdx.x * 4 + w;
    if (n >= NN) return;
    int s = off[n], e = off[n + 1];
    float fsum = 0.f;
    for (int i = s + j; i < e; i += 64) fsum += predv[i];
    for (int m = 1; m < 64; m <<= 1) fsum += __shfl_xor(fsum, m, 64);
    const float* wrow = p1W + j * 65;
    const ushort* ev = embh + (size_t)n * 64;
    float acc = p1b[j];
    #pragma unroll
    for (int f4 = 0; f4 < 16; f4++) {
        uint2 u = *(const uint2*)(ev + f4 * 4);
        acc += wrow[f4 * 4 + 0] * __uint_as_float(u.x << 16);
        acc += wrow[f4 * 4 + 1] * __uint_as_float(u.x & 0xFFFF0000u);
        acc += wrow[f4 * 4 + 2] * __uint_as_float(u.y << 16);
        acc += wrow[f4 * 4 + 3] * __uint_as_float(u.y & 0xFFFF0000u);
    }
    acc += wrow[64] * fsum;
    float val = p2W[j] * fmaxf(acc, 0.f);
    for (int m = 1; m < 64; m <<= 1) val += __shfl_xor(val, m, 64);
    if (j == 0) out[n] = val + p2b[0];
}

extern "C" void kernel_launch(void* const* d_in, const int* in_sizes, int n_in,
                              void* d_out, int out_size, void* d_ws, size_t ws_size,
                              hipStream_t stream) {
    (void)in_sizes; (void)n_in; (void)out_size;
    const float* x    = (const float*)d_in[0];
    const float* ea   = (const float*)d_in[1];
    const float* gcnW = (const float*)d_in[2];
    const float* gcnb = (const float*)d_in[3];
    const float* Wih  = (const float*)d_in[4];
    const float* Whh  = (const float*)d_in[5];
    const float* bih  = (const float*)d_in[6];
    const float* bhh  = (const float*)d_in[7];
    const float* e1W  = (const float*)d_in[8];
    const float* e1b  = (const float*)d_in[9];
    const float* e2W  = (const float*)d_in[10];
    const float* e2b  = (const float*)d_in[11];
    const float* p1W  = (const float*)d_in[12];
    const float* p1b  = (const float*)d_in[13];
    const float* p2W  = (const float*)d_in[14];
    const float* p2b  = (const float*)d_in[15];
    const int*   ei   = (const int*)d_in[16];

    char* ws = (char*)d_ws;
    float*  dinv  = (float*)(ws + WS_DINV);
    float*  snorm = (float*)(ws + WS_SNORM);
    float*  wc    = (float*)(ws + WS_WC);
    float*  wb    = (float*)(ws + WS_WB);
    float*  w1ea  = (float*)(ws + WS_W1EA);
    float2* b1w2  = (float2*)(ws + WS_B1W2);
    float*  biasA = (float*)(ws + WS_BA);
    float*  biasB = (float*)(ws + WS_BB);
    ushort* embh  = (ushort*)(ws + WS_EMB);
    int*    off   = (int*)(ws + WS_OFF);
    int*    cur   = (int*)(ws + WS_CUR);
    int*    rowv  = (int*)(ws + WS_ROWV);
    int*    colv  = (int*)(ws + WS_COLV);
    int*    eidv  = (int*)(ws + WS_EIDV);
    float*  nrmv  = (float*)(ws + WS_NRMV);
    ushort* wfh   = (ushort*)(ws + WS_WFH);
    ushort* wfl   = (ushort*)(ws + WS_WFL);
    ushort* weh   = (ushort*)(ws + WS_WEH);
    ushort* aggh  = (ushort*)(ws + WS_AGGH);
    ushort* aggl  = (ushort*)(ws + WS_AGGL);
    float*  predv = (float*)(ws + WS_PREDV);
    ushort* xb    = (ushort*)(ws + WS_XB);

    float* pred_node = (float*)d_out;
    float* pred_edge = (float*)d_out + NN;

    k_init<<<(NN + 255) / 256, 256, 0, stream>>>(dinv);
    k_deg<<<(EE + 255) / 256, 256, 0, stream>>>(ei, dinv);
    k_scan<<<1, 1024, 0, stream>>>(dinv, off, cur);
    k_dinv<<<(NN + 255) / 256, 256, 0, stream>>>(dinv);
    k_prep<<<13, 256, 0, stream>>>(Wih, gcnW, gcnb, wc, wb);
    k_prep3<<<10, 256, 0, stream>>>(Whh, wc, wb, bih, bhh, wfh, wfl, biasA, biasB);
    k_prepw<<<67, 256, 0, stream>>>(e1W, e1b, e2W, weh, w1ea, b1w2);
    k_fill<<<(EE + 255) / 256, 256, 0, stream>>>(ei, dinv, cur, rowv, colv, eidv, nrmv);
    if (ws_size >= (size_t)WS_XB_END) {
        k_cvtx2<<<NN / 4, 256, 0, stream>>>(x, xb);
        k_gather5<<<NN / 4, 256, 0, stream>>>(xb, dinv, off, rowv, nrmv, aggh, aggl, snorm);
    } else {
        k_gather4<<<(NN / 4) * 8, 256, 0, stream>>>(x, dinv, off, rowv, nrmv, aggh, aggl, snorm);
    }
    k_gru9<<<(NN + 63) / 64, 256, 0, stream>>>(aggh, aggl, snorm, wfh, wfl, biasA, biasB, embh);
    k_edge2<<<EE / 128, 256, 0, stream>>>(embh, ea, weh, w1ea, b1w2,
                                          rowv, colv, eidv, e2b, pred_edge, predv);
    k_node<<<(NN + 3) / 4, 256, 0, stream>>>(embh, predv, off, p1W, p1b, p2W, p2b, pred_node);
}